// Round 1
// 52.004 us; speedup vs baseline: 1.0120x; 1.0120x over previous
//
#include <hip/hip_runtime.h>

// Complex 2x nearest-neighbor upsample, PLANAR output layout:
//   out = stack([y.real, y.imag]) -> (2, B, 2H, 2W, C) float32
//
// RESTRUCTURED (R1): one thread per INPUT float4 (b, hi, wi, g).
//   2 float4 loads (re, im)  — every input cache line read exactly ONCE
//   8 float4 stores          — the 2x2 output block, both planes
// This removes the 4x read amplification of the previous version (one
// thread per OUTPUT float4), cutting L1/L2 read-request traffic from
// 512 MiB to 128 MiB and load instruction count by 4x. Store addresses
// per wave: 4 contiguous 256B segments (full lines) -> full coalescing.

#define BB 16
#define HH 128
#define WW 128
#define CC 64
#define OH (2 * HH)   // 256
#define OW (2 * WW)   // 256

typedef float vfloat4 __attribute__((ext_vector_type(4)));

__global__ __launch_bounds__(256) void complex_upsample2x_planar_rw1(
    const float* __restrict__ x_re,
    const float* __restrict__ x_im,
    float* __restrict__ out,
    unsigned in_vec4,       // B*H*W*C/4   = 4,194,304
    unsigned plane_vec4,    // B*OH*OW*C/4 = 16,777,216
    int n_planes) {
    const unsigned q = blockIdx.x * blockDim.x + threadIdx.x;
    if (q >= in_vec4) return;

    // q -> (b, hi, wi, g): input float4 index IS q (layout matches).
    const unsigned g    = q & (CC / 4 - 1);  // channel group (4 channels)
    const unsigned ipix = q >> 4;
    const unsigned wi   = ipix & (WW - 1);
    const unsigned rem  = ipix >> 7;         // log2(WW) = 7
    const unsigned hi   = rem & (HH - 1);
    const unsigned b    = rem >> 7;          // log2(HH) = 7

    // Output float4 index of the top-left of the 2x2 block:
    //   ((b*OH + 2*hi)*OW + 2*wi)*(CC/4) + g
    const unsigned orow = (b << 8) + (hi << 1);          // b*OH + 2*hi
    const unsigned o00  = (orow << 12) + (wi << 5) + g;  // orow*OW*16 + 2*wi*16 + g
    const unsigned ROWSTEP = OW * (CC / 4);              // 4096 float4 per output row

    const vfloat4 re = *(reinterpret_cast<const vfloat4*>(x_re) + q);
    vfloat4* outv = reinterpret_cast<vfloat4*>(out);

    __builtin_nontemporal_store(re, outv + o00);
    __builtin_nontemporal_store(re, outv + o00 + (CC / 4));
    __builtin_nontemporal_store(re, outv + o00 + ROWSTEP);
    __builtin_nontemporal_store(re, outv + o00 + ROWSTEP + (CC / 4));

    if (n_planes == 2) {
        const vfloat4 im = *(reinterpret_cast<const vfloat4*>(x_im) + q);
        vfloat4* outp = outv + plane_vec4;
        __builtin_nontemporal_store(im, outp + o00);
        __builtin_nontemporal_store(im, outp + o00 + (CC / 4));
        __builtin_nontemporal_store(im, outp + o00 + ROWSTEP);
        __builtin_nontemporal_store(im, outp + o00 + ROWSTEP + (CC / 4));
    }
}

extern "C" void kernel_launch(void* const* d_in, const int* in_sizes, int n_in,
                              void* d_out, int out_size, void* d_ws, size_t ws_size,
                              hipStream_t stream) {
    const float* x_re = (const float*)d_in[0];
    const float* x_im = (const float*)d_in[1];
    float* out = (float*)d_out;

    const unsigned plane_elems = BB * OH * OW * CC;            // 67,108,864
    const int n_planes = (out_size >= (int64_t)2 * plane_elems) ? 2 : 1;
    const unsigned plane_vec4 = plane_elems / 4;               // 16,777,216
    const unsigned in_vec4 = (BB * HH * WW * CC) / 4;          // 4,194,304

    const int block = 256;
    const unsigned grid = (in_vec4 + block - 1) / block;       // 16,384 blocks
    complex_upsample2x_planar_rw1<<<grid, block, 0, stream>>>(
        x_re, x_im, out, in_vec4, plane_vec4, n_planes);
}